// Round 14
// baseline (273.918 us; speedup 1.0000x reference)
//
#include <hip/hip_runtime.h>

// ---------------------------------------------------------------------------
// GQA block: out = Attn(x@Wq^T, x@Wk^T, x@Wv^T; sliding-window+sink) @ Wo^T
// B=2 T=2048 C=2048, NH=16 NKV=4 HS=128, WINDOW=1024 SINK=4.
// R21: attn K moved from LDS to REGISTERS. Per block-chunk the 4 waves each
// re-read the identical 16 K fragments from LDS (half of the ~1630cyc LDS
// time that floors attn at ~24us). Now each wave holds K in 16 bf16x8 regs,
// loaded via 16 coalesced global_load_dwordx4 from L2-resident Kp (single-
// buffered: loads for chunk ci+1 are issued right after QK(ci)'s last read
// of the regs -- WAR keeps order -- and land under softmax+PV, drained by
// the loop-head vmcnt(0)). Removes all K glds + K ds_reads: LDS traffic
// -45%, stage issue halves, LDS 48KB (Vs 32KB + Ps 16KB); Y-epilogue now
// stages in Vs. Rest byte-identical to R20 (1-barrier chunk loop, bn192
// R16, bn128 R13, kvpack R18). Risk: VGPR ~230; spill would regress ->
// revert rule.
// ---------------------------------------------------------------------------

#define T_SEQ 2048
#define NKV   4
#define HS    128
#define CDIM  2048
#define QKVN  3072
#define WIN   1024
#define SINKN 4

typedef __bf16 bf16x8 __attribute__((ext_vector_type(8)));
typedef float  f32x4  __attribute__((ext_vector_type(4)));

#define MFMA16(A, B, C) __builtin_amdgcn_mfma_f32_16x16x32_bf16(A, B, C, 0, 0, 0)
#define EXP2(x) __builtin_amdgcn_exp2f(x)

__device__ inline unsigned short f2bu(float f) {  // fp32 -> bf16 bits, RNE
  unsigned int u = __float_as_uint(f);
  u += 0x7fffu + ((u >> 16) & 1u);
  return (unsigned short)(u >> 16);
}
// pack hi16(f0), hi16(f1) -> one u32 (bf16 truncation; bias cancels in O/l)
__device__ inline unsigned int pkhi(float f0, float f1) {
  return __builtin_amdgcn_perm(__float_as_uint(f1), __float_as_uint(f0),
                               0x07060302u);
}
__device__ inline __bf16 us2b(unsigned short u) {
  union { unsigned short u; __bf16 b; } t; t.u = u; return t.b;
}
__device__ inline f32x4 fzero4() { f32x4 z = {0.f, 0.f, 0.f, 0.f}; return z; }

// async global->LDS, 16B/lane. LDS dest is wave-uniform base + lane*16 (m104).
__device__ __forceinline__ void glds16(const void* g, const void* lds_uniform) {
  typedef __attribute__((address_space(1))) void gv;
  typedef __attribute__((address_space(3))) void lv;
  __builtin_amdgcn_global_load_lds((gv*)(unsigned long long)g,
                                   (lv*)(unsigned int)(unsigned long long)lds_uniform,
                                   16, 0, 0);
}

// ---------------- fused fp32 -> bf16 conversion (all 5 inputs) --------------
#define SZ_X  8388608
#define SZ_WQ 4194304
#define SZ_WK 1048576
#define OFF_WQ (SZ_X)
#define OFF_WK (SZ_X + SZ_WQ)
#define OFF_WV (OFF_WK + SZ_WK)
#define OFF_WO (OFF_WV + SZ_WK)
#define SZ_ALL (OFF_WO + SZ_WQ)

__global__ __launch_bounds__(256) void f2b_all(const float* __restrict__ x,
                                               const float* __restrict__ wq,
                                               const float* __restrict__ wk,
                                               const float* __restrict__ wv,
                                               const float* __restrict__ wo,
                                               unsigned short* __restrict__ out,
                                               float qs) {
  int i = (blockIdx.x * 256 + threadIdx.x) * 4;
  const float* src; int off; float sc = 1.0f;
  if (i < OFF_WQ)      { src = x;  off = 0; }
  else if (i < OFF_WK) { src = wq; off = OFF_WQ; sc = qs; }
  else if (i < OFF_WV) { src = wk; off = OFF_WK; }
  else if (i < OFF_WO) { src = wv; off = OFF_WV; }
  else                 { src = wo; off = OFF_WO; }
  float4 v = *reinterpret_cast<const float4*>(src + (i - off));
  ushort4 o;
  o.x = f2bu(v.x * sc); o.y = f2bu(v.y * sc);
  o.z = f2bu(v.z * sc); o.w = f2bu(v.w * sc);
  *reinterpret_cast<ushort4*>(out + i) = o;
}

__device__ inline void storeC(unsigned short* p, float v) { *p = f2bu(v); }
__device__ inline void storeC(float* p, float v) { *p = v; }

// ---------------- C = A (M,K) @ B^T (N,K), 256x192 2-phase (R16) ------------
template <typename OutT>
__global__ __launch_bounds__(512, 2) void gemm_bn192(const unsigned short* __restrict__ A,
                                                     const unsigned short* __restrict__ B,
                                                     OutT* __restrict__ C,
                                                     int M, int N, int K) {
  __shared__ __align__(16) unsigned short As[2][16384];  // [buf][2][256][32]
  __shared__ __align__(16) unsigned short Bs[2][12288];  // [buf][2][192][32]
  const int tid  = threadIdx.x;
  const int wave = tid >> 6, lane = tid & 63;
  const int quad = lane >> 4, l16 = lane & 15;
  const int wmi  = wave >> 1, wni = wave & 1;            // 4M x 2N wave grid
  const int sx   = ((l16 >> 3) & 1) << 5;

  const int tmn  = M >> 8;
  const int qq   = gridDim.x >> 3;
  const int swzb = (blockIdx.x & 7) * qq + (blockIdx.x >> 3);
  const int tm   = (swzb % tmn) << 8;
  const int tn   = (swzb / tmn) * 192;

  const int logl = (lane * 16) ^ (((lane >> 5) & 1) << 5);
  const int srow = logl >> 6;           // 0..15
  const int scol = (logl & 63) >> 1;    // 0..31
  const int NT   = K >> 6;

  auto issueA = [&](int tt, int ch) {
    glds16(&A[(size_t)(tm + (ch & 15) * 16 + srow) * K + (tt << 6) + (ch >> 4) * 32 + scol],
           (const char*)As + ((tt & 1) << 15) + ch * 1024);
  };
  auto issueB = [&](int tt, int kh, int rb) {
    glds16(&B[(size_t)(tn + rb * 16 + srow) * K + (tt << 6) + kh * 32 + scol],
           (const char*)Bs + (tt & 1) * 24576 + (kh * 12 + rb) * 1024);
  };
  const int g3kh = (wave >= 4) ? 1 : 0;
  const int g3rb = (wave >= 4) ? (wave - 4) : (8 + wave);

  auto issueG1 = [&](int tt) {   // 4 loads: kh0 A + kh0 B rows 0-127 + G3
    issueA(tt, wave); issueA(tt, 8 + wave);
    issueB(tt, 0, wave); issueB(tt, g3kh, g3rb);
  };
  auto issueG2 = [&](int tt) {   // 3 loads: kh1 A + kh1 B rows 64-191
    issueA(tt, 16 + wave); issueA(tt, 24 + wave); issueB(tt, 1, 4 + wave);
  };

  f32x4 acc[4][6];
#pragma unroll
  for (int i = 0; i < 4; ++i)
#pragma unroll
    for (int j = 0; j < 6; ++j) acc[i][j] = fzero4();

  // prologue: t0 complete (G1+G2 = 7/wave), then t1.G1 (4/wave); drain t0.
  issueG1(0); issueG2(0);
  if (NT > 1) {
    issueG1(1);
    asm volatile("s_waitcnt vmcnt(4)" ::: "memory");
  } else {
    asm volatile("s_waitcnt vmcnt(0)" ::: "memory");
  }
  __builtin_amdgcn_s_barrier();

  for (int t = 0; t < NT; ++t) {
    const char* Asc = (const char*)As + ((t & 1) << 15);
    const char* Bsc = (const char*)Bs + (t & 1) * 24576;
    const bool h1 = (t + 1 < NT), h2 = (t + 2 < NT);
    bf16x8 aq[4], bq[6];

    // ---- phase 0: kh0 ----
#pragma unroll
    for (int g = 0; g < 6; ++g)
      bq[g] = *reinterpret_cast<const bf16x8*>(
          Bsc + (((wni * 96 + g * 16 + l16) << 6) + ((quad * 16) ^ sx)));
#pragma unroll
    for (int f = 0; f < 4; ++f)
      aq[f] = *reinterpret_cast<const bf16x8*>(
          Asc + (((wmi * 64 + f * 16 + l16) << 6) + ((quad * 16) ^ sx)));
    if (h1) issueG2(t + 1);   // idle buffer; its readers done >=1 barrier ago
    __builtin_amdgcn_s_setprio(1);
#pragma unroll
    for (int f = 0; f < 4; ++f)
#pragma unroll
      for (int g = 0; g < 6; ++g) acc[f][g] = MFMA16(aq[f], bq[g], acc[f][g]);
    __builtin_amdgcn_s_setprio(0);
    if (h1) asm volatile("s_waitcnt vmcnt(7)" ::: "memory");
    else    asm volatile("s_waitcnt vmcnt(0)" ::: "memory");
    __builtin_amdgcn_s_barrier();

    // ---- phase 1: kh1 ----
#pragma unroll
    for (int g = 0; g < 6; ++g)
      bq[g] = *reinterpret_cast<const bf16x8*>(
          Bsc + (12288 + ((wni * 96 + g * 16 + l16) << 6) + ((quad * 16) ^ sx)));
#pragma unroll
    for (int f = 0; f < 4; ++f)
      aq[f] = *reinterpret_cast<const bf16x8*>(
          Asc + (16384 + ((wmi * 64 + f * 16 + l16) << 6) + ((quad * 16) ^ sx)));
    if (h2) issueG1(t + 2);
    __builtin_amdgcn_s_setprio(1);
#pragma unroll
    for (int f = 0; f < 4; ++f)
#pragma unroll
      for (int g = 0; g < 6; ++g) acc[f][g] = MFMA16(aq[f], bq[g], acc[f][g]);
    __builtin_amdgcn_s_setprio(0);
    if (h2)      asm volatile("s_waitcnt vmcnt(7)" ::: "memory");
    else if (h1) asm volatile("s_waitcnt vmcnt(3)" ::: "memory");
    else         asm volatile("s_waitcnt vmcnt(0)" ::: "memory");
    __builtin_amdgcn_s_barrier();
  }

  // ---- epilogue ----
#pragma unroll
  for (int fi = 0; fi < 4; ++fi)
#pragma unroll
    for (int g = 0; g < 6; ++g)
#pragma unroll
      for (int r = 0; r < 4; ++r) {
        const int row = tm + wmi * 64 + fi * 16 + quad * 4 + r;
        const int col = tn + wni * 96 + g * 16 + l16;
        storeC(&C[(size_t)row * N + col], acc[fi][g][r]);
      }
}

// ---------------- C = A (M,K) @ B^T (N,K), 256x128 2-phase (R13) ------------
template <typename OutT>
__global__ __launch_bounds__(512, 2) void gemm_bn128(const unsigned short* __restrict__ A,
                                                     const unsigned short* __restrict__ B,
                                                     OutT* __restrict__ C,
                                                     int M, int N, int K) {
  __shared__ __align__(16) unsigned short As[2][16384];  // [buf][2][256][32]
  __shared__ __align__(16) unsigned short Bs[2][8192];   // [buf][2][128][32]
  const int tid  = threadIdx.x;
  const int wave = tid >> 6, lane = tid & 63;
  const int quad = lane >> 4, l16 = lane & 15;
  const int wmi  = wave >> 1, wni = wave & 1;            // 4M x 2N wave grid
  const int sx   = ((l16 >> 3) & 1) << 5;

  const int tmn  = M >> 8;
  const int qq   = gridDim.x >> 3;
  const int swzb = (blockIdx.x & 7) * qq + (blockIdx.x >> 3);
  const int tm   = (swzb % tmn) << 8;
  const int tn   = (swzb / tmn) << 7;

  const int logl = (lane * 16) ^ (((lane >> 5) & 1) << 5);
  const int srow = logl >> 6;           // 0..15
  const int scol = (logl & 63) >> 1;    // 0..31
  const int NT   = K >> 6;

  auto issueA = [&](int tt, int ch) {
    glds16(&A[(size_t)(tm + (ch & 15) * 16 + srow) * K + (tt << 6) + (ch >> 4) * 32 + scol],
           (const char*)As + ((tt & 1) << 15) + ch * 1024);
  };
  auto issueB = [&](int tt, int ch) {
    glds16(&B[(size_t)(tn + (ch & 7) * 16 + srow) * K + (tt << 6) + (ch >> 3) * 32 + scol],
           (const char*)Bs + ((tt & 1) << 14) + ch * 1024);
  };

  f32x4 acc[4][4];
#pragma unroll
  for (int i = 0; i < 4; ++i)
#pragma unroll
    for (int j = 0; j < 4; ++j) acc[i][j] = fzero4();

  // prologue: t0-kh0, t0-kh1, t1-kh0 (3 groups x 3 chunks/wave)
  issueB(0, wave);     issueA(0, wave);      issueA(0, 8 + wave);
  issueB(0, 8 + wave); issueA(0, 16 + wave); issueA(0, 24 + wave);
  if (NT > 1) {
    issueB(1, wave); issueA(1, wave); issueA(1, 8 + wave);
    asm volatile("s_waitcnt vmcnt(6)" ::: "memory");
  } else {
    asm volatile("s_waitcnt vmcnt(3)" ::: "memory");
  }
  __builtin_amdgcn_s_barrier();

  for (int t = 0; t < NT; ++t) {
    const char* Asc = (const char*)As + ((t & 1) << 15);
    const char* Bsc = (const char*)Bs + ((t & 1) << 14);
    const bool h1 = (t + 1 < NT), h2 = (t + 2 < NT);
    bf16x8 aq[4], bq[4];

    // ---- phase 0: kh0 ----
#pragma unroll
    for (int g = 0; g < 4; ++g)
      bq[g] = *reinterpret_cast<const bf16x8*>(
          Bsc + (((wni * 64 + g * 16 + l16) << 6) + ((quad * 16) ^ sx)));
#pragma unroll
    for (int f = 0; f < 4; ++f)
      aq[f] = *reinterpret_cast<const bf16x8*>(
          Asc + (((wmi * 64 + f * 16 + l16) << 6) + ((quad * 16) ^ sx)));
    if (h1) {  // (t+1)-kh1 -> idle buffer
      issueB(t + 1, 8 + wave); issueA(t + 1, 16 + wave); issueA(t + 1, 24 + wave);
    }
    __builtin_amdgcn_s_barrier();
    asm volatile("s_waitcnt lgkmcnt(0)" ::: "memory");
    __builtin_amdgcn_s_setprio(1);
#pragma unroll
    for (int f = 0; f < 4; ++f)
#pragma unroll
      for (int g = 0; g < 4; ++g) acc[f][g] = MFMA16(aq[f], bq[g], acc[f][g]);
    __builtin_amdgcn_s_setprio(0);
    if (h1) asm volatile("s_waitcnt vmcnt(6)" ::: "memory");
    else    asm volatile("s_waitcnt vmcnt(0)" ::: "memory");
    __builtin_amdgcn_s_barrier();

    // ---- phase 1: kh1 ----
#pragma unroll
    for (int g = 0; g < 4; ++g)
      bq[g] = *reinterpret_cast<const bf16x8*>(
          Bsc + (8192 + ((wni * 64 + g * 16 + l16) << 6) + ((quad * 16) ^ sx)));
#pragma unroll
    for (int f = 0; f < 4; ++f)
      aq[f] = *reinterpret_cast<const bf16x8*>(
          Asc + (16384 + ((wmi * 64 + f * 16 + l16) << 6) + ((quad * 16) ^ sx)));
    if (h2) {  // (t+2)-kh0 -> current buffer; reads retired at ph0 barrier.
      issueB(t + 2, wave); issueA(t + 2, wave); issueA(t + 2, 8 + wave);
    }
    __builtin_amdgcn_s_barrier();
    asm volatile("s_waitcnt lgkmcnt(0)" ::: "memory");
    __builtin_amdgcn_s_setprio(1);
#pragma unroll
    for (int f = 0; f < 4; ++f)
#pragma unroll
      for (int g = 0; g < 4; ++g) acc[f][g] = MFMA16(aq[f], bq[g], acc[f][g]);
    __builtin_amdgcn_s_setprio(0);
    if (h2)      asm volatile("s_waitcnt vmcnt(6)" ::: "memory");
    else if (h1) asm volatile("s_waitcnt vmcnt(3)" ::: "memory");
    else         asm volatile("s_waitcnt vmcnt(0)" ::: "memory");
    __builtin_amdgcn_s_barrier();
  }

  // ---- epilogue ----
#pragma unroll
  for (int fi = 0; fi < 4; ++fi)
#pragma unroll
    for (int g = 0; g < 4; ++g)
#pragma unroll
      for (int r = 0; r < 4; ++r) {
        const int row = tm + wmi * 64 + fi * 16 + quad * 4 + r;
        const int col = tn + wni * 64 + g * 16 + l16;
        storeC(&C[(size_t)row * N + col], acc[fi][g][r]);
      }
}

// ---------------- K/V fragment packing, LDS-bounced (R18) -------------------
__global__ __launch_bounds__(256) void kvpack(const unsigned short* __restrict__ QKV,
                                              unsigned short* __restrict__ Kp,
                                              unsigned short* __restrict__ Vp) {
  __shared__ __align__(16) unsigned short Kl[8192];   // packed K image, 16KB
  __shared__ __align__(16) unsigned short Vl[8192];   // packed V image (2 kt32)
  const int tid  = threadIdx.x;
  const int kt64 = blockIdx.x;           // 0..31
  const int bk   = blockIdx.y;           // b*4 + kvh
  const int b = bk >> 2, kvh = bk & 3;
  const int kt = kt64 * 64;
  const int bT = b * T_SEQ;
  const int dq = tid & 15;               // dim octet: dims dq*8..dq*8+7

  // ---- K: float4 (8 dims = 8 packed-contiguous elems) -> swizzled LDS ----
#pragma unroll
  for (int it = 0; it < 4; ++it) {
    int key = it * 16 + (tid >> 4);      // 0..63
    float4 v = *reinterpret_cast<const float4*>(
        &QKV[(size_t)(bT + kt + key) * QKVN + 2048 + kvh * HS + dq * 8]);
    int c = dq >> 2, quad = dq & 3, nt = key & 3, l16s = key >> 2;
    int byte = ((c * 4 + nt) * 64 + quad * 16 + l16s) * 16;   // elem*2, j=0
    byte ^= ((byte >> 8) & 7) << 4;
    *reinterpret_cast<float4*>((char*)Kl + byte) = v;
  }

  // ---- V: key-pairs -> u32 per dim -> swizzled LDS ----
#pragma unroll
  for (int it = 0; it < 2; ++it) {
    int kp   = it * 16 + (tid >> 4);     // key pair 0..31; keys 2kp, 2kp+1
    int key0 = kp * 2;
    float4 v0 = *reinterpret_cast<const float4*>(
        &QKV[(size_t)(bT + kt + key0) * QKVN + 2560 + kvh * HS + dq * 8]);
    float4 v1 = *reinterpret_cast<const float4*>(
        &QKV[(size_t)(bT + kt + key0 + 1) * QKVN + 2560 + kvh * HS + dq * 8]);
    const unsigned short* p0 = reinterpret_cast<const unsigned short*>(&v0);
    const unsigned short* p1 = reinterpret_cast<const unsigned short*>(&v1);
    int qv  = (kp & 15) >> 2;            // (key0&31)>>3 (key0 even)
    int jv  = (kp & 3) * 2;              // key0&7, even
    int blk = kp >> 4;                   // key0>>5
#pragma unroll
    for (int j2 = 0; j2 < 8; ++j2) {
      int d = dq * 8 + j2, dt = d >> 4, l16v = d & 15;
      int byte = (blk * 4096 + (dt * 64 + qv * 16 + l16v) * 8 + jv) * 2;
      byte ^= ((byte >> 8) & 7) << 4;
      unsigned int u = (unsigned int)p0[j2] | ((unsigned int)p1[j2] << 16);
      *reinterpret_cast<unsigned int*>((char*)Vl + byte) = u;
    }
  }
  __syncthreads();

  // ---- coalesced store-out: linear global, swizzled LDS read ----
  char* kdst = (char*)&Kp[(size_t)(bk * 32 + kt64) * 8192];
  char* vdst = (char*)&Vp[(size_t)(bk * 64 + kt64 * 2) * 4096];  // 2 blocks contiguous
#pragma unroll
  for (int it = 0; it < 4; ++it) {
    int byte = it * 4096 + tid * 16;
    int sb   = byte ^ (((byte >> 8) & 7) << 4);
    *reinterpret_cast<uint4*>(kdst + byte) =
        *reinterpret_cast<const uint4*>((const char*)Kl + sb);
    *reinterpret_cast<uint4*>(vdst + byte) =
        *reinterpret_cast<const uint4*>((const char*)Vl + sb);
  }
}

// ---------------- flash attention, K-in-registers (R21) ---------------------
// grid 512 = 64 q-tiles x 8 (b,kvh); bk = blockIdx.x & 7 -> XCD-resident K/V.
// block 256 = 4 waves = 4 heads of the group, same 32 queries. Per chunk:
// vmcnt(0) drains this wave's V-glds AND K-reg loads (issued a full chunk
// ago); barrier publishes V parts + retires all buf^1 reads; stage V(ci+1);
// QK from K-regs; issue K-reg loads (ci+1) (WAR after last use); softmax;
// PV from LDS V. K loads: 16 coalesced global_load_dwordx4 per wave from
// packed Kp (frag f: lane reads Kp + frag*1024 + lane*16).
__global__ __launch_bounds__(256) void attn_kernel(const unsigned short* __restrict__ QKV,
                                                   const unsigned short* __restrict__ Kp,
                                                   const unsigned short* __restrict__ Vp,
                                                   unsigned short* __restrict__ Y) {
  __shared__ __align__(16) unsigned short Vs[2][8192];
  __shared__ __align__(16) unsigned short Ps[4 * 2048];   // [wave][32][64]

  const int tid  = threadIdx.x;
  const int wave = tid >> 6, lane = tid & 63;
  const int quad = lane >> 4, l16 = lane & 15;
  const int bk   = blockIdx.x & 7;                        // XCD-resident group
  const int seq  = blockIdx.x >> 3;                       // 0..63
  const int qt0  = (63 - seq) * 32;                       // long blocks first
  const int kvh  = bk & 3, b = bk >> 2;
  const int h    = kvh * 4 + wave;
  const int bT   = b * T_SEQ;
  char* Pw = (char*)&Ps[wave * 2048];

  // Q fragments (A-operand: m=l16, k=quad*8+j); Q pre-scaled by log2e/sqrt(HS)
  bf16x8 qa[2][4];
#pragma unroll
  for (int mt = 0; mt < 2; ++mt)
#pragma unroll
    for (int c = 0; c < 4; ++c)
      qa[mt][c] = *reinterpret_cast<const bf16x8*>(
          &QKV[(size_t)(bT + qt0 + mt * 16 + l16) * QKVN + h * HS + c * 32 + quad * 8]);

  bf16x8 ones;
#pragma unroll
  for (int j = 0; j < 8; ++j) ones[j] = us2b(0x3F80);  // bf16 1.0

  f32x4 o[2][9];   // [mt][dt]; dt=8 accumulates row-sum l
#pragma unroll
  for (int mt = 0; mt < 2; ++mt)
#pragma unroll
    for (int dt = 0; dt < 9; ++dt) o[mt][dt] = fzero4();

  const int start = (qt0 >= 1024) ? ((qt0 - 1023) & ~63) : 0;
  const int sink  = (start > 0) ? 1 : 0;
  const int nch   = ((qt0 + 32 - start + 63) >> 6) + sink;

  const unsigned short* Kbase = &Kp[(size_t)bk * 32 * 8192 + lane * 8];
  const unsigned short* Vbase = &Vp[(size_t)bk * 64 * 4096 + lane * 8];

  auto chunk_kt = [&](int ci) {
    return (sink && ci == 0) ? 0 : start + (ci - sink) * 64;
  };

  // stage chunk ci's V into LDS buffer buf (4 glds16/wave)
  auto stageV = [&](int ci, int buf) {
    const unsigned short* vg = Vbase + (size_t)(chunk_kt(ci) >> 5) * 4096;
#pragma unroll
    for (int i = 0; i < 4; ++i) {
      int part = wave * 4 + i;                    // wave-uniform
      glds16(vg + part * 512, &Vs[buf][part * 512]);
    }
  };

  // K fragments in registers, single-buffered (16 bf16x8 = 64 VGPR)
  bf16x8 kr[16];
  auto loadK = [&](int ci) {
    const unsigned short* kg = Kbase + (size_t)(chunk_kt(ci) >> 6) * 8192;
#pragma unroll
    for (int f = 0; f < 16; ++f)
      kr[f] = *reinterpret_cast<const bf16x8*>(kg + f * 512);
  };

  stageV(0, 0);
  loadK(0);

  for (int ci = 0; ci < nch; ++ci) {
    const int  buf = ci & 1;
    const bool is_sink = (sink && ci == 0);
    const int  kt  = chunk_kt(ci);
    const int  rem = qt0 + 32 - kt;
    const int  kcmax = is_sink ? 1 : (rem >= 64 ? 2 : ((rem + 31) >> 5));
    const bool full  = !is_sink && (kt + 63 <= qt0) && (kt >= qt0 - 992);

    // drain own V-glds(ci) + K-reg loads(ci) (issued a full chunk ago).
    asm volatile("s_waitcnt vmcnt(0)" ::: "memory");
    __builtin_amdgcn_s_barrier();
    // barrier proves all waves' reads of Vs[buf^1] retired -> restage safe.
    if (ci + 1 < nch) stageV(ci + 1, buf ^ 1);

    // ---- S = Q K^T from registers ----
    f32x4 s[2][4];
#pragma unroll
    for (int nt = 0; nt < 4; ++nt) { s[0][nt] = fzero4(); s[1][nt] = fzero4(); }
    __builtin_amdgcn_s_setprio(1);
#pragma unroll
    for (int c = 0; c < 4; ++c) {
#pragma unroll
      for (int nt = 0; nt < 4; ++nt) {
        s[0][nt] = MFMA16(qa[0][c], kr[c * 4 + nt], s[0][nt]);
        s[1][nt] = MFMA16(qa[1][c], kr[c * 4 + nt], s[1][nt]);
      }
    }
    __builtin_amdgcn_s_setprio(0);
    // kr dead now: issue next chunk's K loads (WAR keeps them after the
    // MFMAs); they land during softmax+PV+barrier, drained at loop head.
    if (ci + 1 < nch) loadK(ci + 1);

    // ---- P = exp2(S) with mask (key of col: kt + l16*4 + nt) ----
    if (full) {
#pragma unroll
      for (int mt = 0; mt < 2; ++mt)
#pragma unroll
        for (int r = 0; r < 4; ++r) {
          const int row = mt * 16 + quad * 4 + r;
          uint2 pk;
          pk.x = pkhi(EXP2(s[mt][0][r]), EXP2(s[mt][1][r]));
          pk.y = pkhi(EXP2(s[mt][2][r]), EXP2(s[mt][3][r]));
          *reinterpret_cast<uint2*>(
              Pw + ((row * 128 + l16 * 8) ^ ((row & 7) << 4))) = pk;
        }
    } else {
#pragma unroll
      for (int mt = 0; mt < 2; ++mt)
#pragma unroll
        for (int r = 0; r < 4; ++r) {
          const int row = mt * 16 + quad * 4 + r;
          const int qi  = qt0 + row;
          float p[4];
#pragma unroll
          for (int nt = 0; nt < 4; ++nt) {
            int kj = kt + l16 * 4 + nt;
            bool ok = ((kj <= qi) && (kj + (WIN - 1) >= qi)) ||
                      ((kj < SINKN) && (qi >= SINKN));
            p[nt] = ok ? EXP2(s[mt][nt][r]) : 0.f;
          }
          uint2 pk;
          pk.x = pkhi(p[0], p[1]);
          pk.y = pkhi(p[2], p[3]);
          *reinterpret_cast<uint2*>(
              Pw + ((row * 128 + l16 * 8) ^ ((row & 7) << 4))) = pk;
        }
    }
    asm volatile("s_waitcnt lgkmcnt(0)" ::: "memory");  // wave-local P drain

    // ---- O += P V (+ ones column for l), V from LDS ----
    __builtin_amdgcn_s_setprio(1);
#pragma unroll
    for (int kc = 0; kc < 2; ++kc)
      if (kc < kcmax) {
#pragma unroll
        for (int mt = 0; mt < 2; ++mt) {
          const int prow = mt * 16 + l16;
          bf16x8 pf = *reinterpret_cast<const bf16x8*>(
              Pw + ((prow * 128 + kc * 64 + quad * 16) ^ ((prow & 7) << 4)));
#pragma unroll
          for (int dt = 0; dt < 8; ++dt) {
            bf16x8 vf = *reinterpret_cast<const bf16x8*>(
                &Vs[buf][kc * 4096 + dt * 512 + lane * 8]);
            o[mt][dt] = MFMA16(pf, vf, o[mt][dt]);
          }
          o[mt][8] = MFMA16(pf, ones, o[mt][8]);
        }
      }
    __builtin_amdgcn_s_setprio(0);
  }

  // ---- normalize, stage in LDS (reuse Vs, 32KB), coalesced Y store ----
  __syncthreads();                       // full drain before buffer reuse
  unsigned short* Yst = &Vs[0][0];       // 32 rows x 512 cols (32KB)
#pragma unroll
  for (int mt = 0; mt < 2; ++mt) {
    float inv[4];
#pragma unroll
    for (int r = 0; r < 4; ++r) inv[r] = __builtin_amdgcn_rcpf(o[mt][8][r]);
#pragma unroll
    for (int dt = 0; dt < 8; ++dt)
#pragma unroll
      for (int r = 0; r < 4; ++r)
        Yst[(mt * 16 + quad * 4 + r) * 512 + wave * 128 + dt * 16 + l16] =
            f2bu(o[mt][dt][r] * inv[r]);
  }
  __syncthreads();
#pragma unroll
  for (int it = 0; it < 8; ++it) {
    int idx = it * 256 + tid;
    int row = idx >> 6, col = (idx & 63) * 8;
    *reinterpret_cast<uint4*>(
        &Y[(size_t)(bT + qt0 + row) * CDIM + kvh * 512 + col]) =
        *reinterpret_cast<const uint4*>(&Yst[row * 512 + col]);
  }
}

// ---------------------------------------------------------------------------
extern "C" void kernel_launch(void* const* d_in, const int* in_sizes, int n_in,
                              void* d_out, int out_size, void* d_ws, size_t ws_size,
                              hipStream_t stream) {
  const float* x  = (const float*)d_in[0];
  const float* Wq = (const float*)d_in[1];
  const float* Wk = (const float*)d_in[2];
  const float* Wv = (const float*)d_in[3];
  const float* Wo = (const float*)d_in[4];
  float* out = (float*)d_out;

  // workspace layout (bf16 elems); total 62.9 MB
  unsigned short* base = (unsigned short*)d_ws;
  unsigned short* xb   = base;              // x bf16 (8388608); later Y
  unsigned short* wqb  = xb + OFF_WQ;       // Wq bf16; later Kp+Vp
  unsigned short* wob  = xb + OFF_WO;       // Wo bf16
  unsigned short* QKVb = xb + SZ_ALL;       // QKV (4096 x 3072)
  unsigned short* Kpb  = wqb;               // packed K (2097152)
  unsigned short* Vpb  = wqb + 2097152;     // packed V (2097152)
  unsigned short* Yb   = xb;                // attn out (4096 x 2048)

  // 1/sqrt(HS) * log2(e) folded into Wq so exp2 is native
  const float qscale = 0.08838834764831845f * 1.4426950408889634f;
  f2b_all<<<SZ_ALL / 1024, 256, 0, stream>>>(x, Wq, Wk, Wv, Wo, xb, qscale);

  // fused QKV projection: 256x192 tiles -> 16x16 = 256 blocks (full GPU)
  gemm_bn192<unsigned short><<<256, 512, 0, stream>>>(xb, wqb, QKVb, 4096, QKVN, 2048);

  kvpack<<<dim3(32, 8), 256, 0, stream>>>(QKVb, Kpb, Vpb);

  // attention: 1D grid, bk = id&7 -> per-XCD K/V residency
  attn_kernel<<<512, 256, 0, stream>>>(QKVb, Kpb, Vpb, Yb);

  // output projection: 256x128 tiles -> 16x16 = 256 blocks (R13 config)
  gemm_bn128<float><<<256, 512, 0, stream>>>(Yb, wob, out, 4096, 2048, 2048);
}

// Round 15
// 248.161 us; speedup vs baseline: 1.1038x; 1.1038x over previous
//
#include <hip/hip_runtime.h>

// ---------------------------------------------------------------------------
// GQA block: out = Attn(x@Wq^T, x@Wk^T, x@Wv^T; sliding-window+sink) @ Wo^T
// B=2 T=2048 C=2048, NH=16 NKV=4 HS=128, WINDOW=1024 SINK=4.
// R22 = exact revert to R20, the measured best (248.3us). R21's K-in-regs
// regressed attn 40->71us (occupancy 14->8.2%, MfmaUtil 15: single-buffered
// kr[16] serializes the schedule and the per-lane K loads expose an L2
// round-trip per chunk) -- reverted per pre-committed rule. Configuration:
// bn192 R16 (de-serialized, G3-race-fixed, vmcnt(7) ledger), bn128 R13,
// kvpack R18 LDS-bounce, attn R20 (1-barrier chunk loop, double-buffered
// K/V via glds16, XCD-resident K/V, swizzled P).
// ---------------------------------------------------------------------------

#define T_SEQ 2048
#define NKV   4
#define HS    128
#define CDIM  2048
#define QKVN  3072
#define WIN   1024
#define SINKN 4

typedef __bf16 bf16x8 __attribute__((ext_vector_type(8)));
typedef float  f32x4  __attribute__((ext_vector_type(4)));

#define MFMA16(A, B, C) __builtin_amdgcn_mfma_f32_16x16x32_bf16(A, B, C, 0, 0, 0)
#define EXP2(x) __builtin_amdgcn_exp2f(x)

__device__ inline unsigned short f2bu(float f) {  // fp32 -> bf16 bits, RNE
  unsigned int u = __float_as_uint(f);
  u += 0x7fffu + ((u >> 16) & 1u);
  return (unsigned short)(u >> 16);
}
// pack hi16(f0), hi16(f1) -> one u32 (bf16 truncation; bias cancels in O/l)
__device__ inline unsigned int pkhi(float f0, float f1) {
  return __builtin_amdgcn_perm(__float_as_uint(f1), __float_as_uint(f0),
                               0x07060302u);
}
__device__ inline __bf16 us2b(unsigned short u) {
  union { unsigned short u; __bf16 b; } t; t.u = u; return t.b;
}
__device__ inline f32x4 fzero4() { f32x4 z = {0.f, 0.f, 0.f, 0.f}; return z; }

// async global->LDS, 16B/lane. LDS dest is wave-uniform base + lane*16 (m104).
__device__ __forceinline__ void glds16(const void* g, const void* lds_uniform) {
  typedef __attribute__((address_space(1))) void gv;
  typedef __attribute__((address_space(3))) void lv;
  __builtin_amdgcn_global_load_lds((gv*)(unsigned long long)g,
                                   (lv*)(unsigned int)(unsigned long long)lds_uniform,
                                   16, 0, 0);
}

// ---------------- fused fp32 -> bf16 conversion (all 5 inputs) --------------
#define SZ_X  8388608
#define SZ_WQ 4194304
#define SZ_WK 1048576
#define OFF_WQ (SZ_X)
#define OFF_WK (SZ_X + SZ_WQ)
#define OFF_WV (OFF_WK + SZ_WK)
#define OFF_WO (OFF_WV + SZ_WK)
#define SZ_ALL (OFF_WO + SZ_WQ)

__global__ __launch_bounds__(256) void f2b_all(const float* __restrict__ x,
                                               const float* __restrict__ wq,
                                               const float* __restrict__ wk,
                                               const float* __restrict__ wv,
                                               const float* __restrict__ wo,
                                               unsigned short* __restrict__ out,
                                               float qs) {
  int i = (blockIdx.x * 256 + threadIdx.x) * 4;
  const float* src; int off; float sc = 1.0f;
  if (i < OFF_WQ)      { src = x;  off = 0; }
  else if (i < OFF_WK) { src = wq; off = OFF_WQ; sc = qs; }
  else if (i < OFF_WV) { src = wk; off = OFF_WK; }
  else if (i < OFF_WO) { src = wv; off = OFF_WV; }
  else                 { src = wo; off = OFF_WO; }
  float4 v = *reinterpret_cast<const float4*>(src + (i - off));
  ushort4 o;
  o.x = f2bu(v.x * sc); o.y = f2bu(v.y * sc);
  o.z = f2bu(v.z * sc); o.w = f2bu(v.w * sc);
  *reinterpret_cast<ushort4*>(out + i) = o;
}

__device__ inline void storeC(unsigned short* p, float v) { *p = f2bu(v); }
__device__ inline void storeC(float* p, float v) { *p = v; }

// ---------------- C = A (M,K) @ B^T (N,K), 256x192 2-phase (R16) ------------
// Requires M%256==0, N%192==0, K%64==0, grid=(M/256)*(N/192), grid%8==0.
// LDS: As [buf][kh:2][256][32], Bs [buf][kh:2][192][32]; 64B rows, XOR-bit5
// swizzle (byte ^= row_bit3 << 5). 8 waves as 4Mx2N, per-wave 64x96.
// Groups per wave: G1 (ph1-issued, for t+2) = {A ch wave, A ch 8+wave,
// B(0,wave), G3}; G2 (ph0-issued, for t+1) = {A ch 16+wave, A ch 24+wave,
// B(1,4+wave)}. G3: waves 0-3 -> B(0, 8+wave); waves 4-7 -> B(1, wave-4).
// De-serialized: no opening barrier, no forced lgkm (compiler emits partial
// waits); closing barrier + vmcnt ledger gate all hazards.
template <typename OutT>
__global__ __launch_bounds__(512, 2) void gemm_bn192(const unsigned short* __restrict__ A,
                                                     const unsigned short* __restrict__ B,
                                                     OutT* __restrict__ C,
                                                     int M, int N, int K) {
  __shared__ __align__(16) unsigned short As[2][16384];  // [buf][2][256][32]
  __shared__ __align__(16) unsigned short Bs[2][12288];  // [buf][2][192][32]
  const int tid  = threadIdx.x;
  const int wave = tid >> 6, lane = tid & 63;
  const int quad = lane >> 4, l16 = lane & 15;
  const int wmi  = wave >> 1, wni = wave & 1;            // 4M x 2N wave grid
  const int sx   = ((l16 >> 3) & 1) << 5;

  const int tmn  = M >> 8;
  const int qq   = gridDim.x >> 3;
  const int swzb = (blockIdx.x & 7) * qq + (blockIdx.x >> 3);
  const int tm   = (swzb % tmn) << 8;
  const int tn   = (swzb / tmn) * 192;

  const int logl = (lane * 16) ^ (((lane >> 5) & 1) << 5);
  const int srow = logl >> 6;           // 0..15
  const int scol = (logl & 63) >> 1;    // 0..31
  const int NT   = K >> 6;

  // A chunk ch in [0,32): kh=ch>>4, rows (ch&15)*16; LDS dst linear ch*1KB.
  auto issueA = [&](int tt, int ch) {
    glds16(&A[(size_t)(tm + (ch & 15) * 16 + srow) * K + (tt << 6) + (ch >> 4) * 32 + scol],
           (const char*)As + ((tt & 1) << 15) + ch * 1024);
  };
  // B chunk (kh, rb): rb in [0,12) -> rows rb*16 of k-half kh; dst linear.
  auto issueB = [&](int tt, int kh, int rb) {
    glds16(&B[(size_t)(tn + rb * 16 + srow) * K + (tt << 6) + kh * 32 + scol],
           (const char*)Bs + (tt & 1) * 24576 + (kh * 12 + rb) * 1024);
  };
  const int g3kh = (wave >= 4) ? 1 : 0;
  const int g3rb = (wave >= 4) ? (wave - 4) : (8 + wave);

  auto issueG1 = [&](int tt) {   // 4 loads: kh0 A + kh0 B rows 0-127 + G3
    issueA(tt, wave); issueA(tt, 8 + wave);
    issueB(tt, 0, wave); issueB(tt, g3kh, g3rb);
  };
  auto issueG2 = [&](int tt) {   // 3 loads: kh1 A + kh1 B rows 64-191
    issueA(tt, 16 + wave); issueA(tt, 24 + wave); issueB(tt, 1, 4 + wave);
  };

  f32x4 acc[4][6];
#pragma unroll
  for (int i = 0; i < 4; ++i)
#pragma unroll
    for (int j = 0; j < 6; ++j) acc[i][j] = fzero4();

  // prologue: t0 complete (G1+G2 = 7/wave), then t1.G1 (4/wave); drain t0.
  issueG1(0); issueG2(0);
  if (NT > 1) {
    issueG1(1);
    asm volatile("s_waitcnt vmcnt(4)" ::: "memory");
  } else {
    asm volatile("s_waitcnt vmcnt(0)" ::: "memory");
  }
  __builtin_amdgcn_s_barrier();

  for (int t = 0; t < NT; ++t) {
    const char* Asc = (const char*)As + ((t & 1) << 15);
    const char* Bsc = (const char*)Bs + (t & 1) * 24576;
    const bool h1 = (t + 1 < NT), h2 = (t + 2 < NT);
    bf16x8 aq[4], bq[6];

    // ---- phase 0: kh0 (G1(t) confirmed at end of ph1(t-1) / prologue) ----
#pragma unroll
    for (int g = 0; g < 6; ++g)
      bq[g] = *reinterpret_cast<const bf16x8*>(
          Bsc + (((wni * 96 + g * 16 + l16) << 6) + ((quad * 16) ^ sx)));
#pragma unroll
    for (int f = 0; f < 4; ++f)
      aq[f] = *reinterpret_cast<const bf16x8*>(
          Asc + (((wmi * 64 + f * 16 + l16) << 6) + ((quad * 16) ^ sx)));
    if (h1) issueG2(t + 1);   // idle buffer; its readers done >=1 barrier ago
    __builtin_amdgcn_s_setprio(1);
#pragma unroll
    for (int f = 0; f < 4; ++f)
#pragma unroll
      for (int g = 0; g < 6; ++g) acc[f][g] = MFMA16(aq[f], bq[g], acc[f][g]);
    __builtin_amdgcn_s_setprio(0);
    // drain G2(t) (issued ph0(t-1)) before ph1 reads kh1; keep G1(t+1)[4] +
    // G2(t+1)[3] = 7.
    if (h1) asm volatile("s_waitcnt vmcnt(7)" ::: "memory");
    else    asm volatile("s_waitcnt vmcnt(0)" ::: "memory");
    __builtin_amdgcn_s_barrier();

    // ---- phase 1: kh1 ----
#pragma unroll
    for (int g = 0; g < 6; ++g)
      bq[g] = *reinterpret_cast<const bf16x8*>(
          Bsc + (12288 + ((wni * 96 + g * 16 + l16) << 6) + ((quad * 16) ^ sx)));
#pragma unroll
    for (int f = 0; f < 4; ++f)
      aq[f] = *reinterpret_cast<const bf16x8*>(
          Asc + (16384 + ((wmi * 64 + f * 16 + l16) << 6) + ((quad * 16) ^ sx)));
    // G1(t+2) -> current-buffer kh0: its reads were consumed before ph0's
    // closing barrier, which precedes this issue.
    if (h2) issueG1(t + 2);
    __builtin_amdgcn_s_setprio(1);
#pragma unroll
    for (int f = 0; f < 4; ++f)
#pragma unroll
      for (int g = 0; g < 6; ++g) acc[f][g] = MFMA16(aq[f], bq[g], acc[f][g]);
    __builtin_amdgcn_s_setprio(0);
    // drain G1(t+1) (issued ph1(t-1)) before next ph0; keep G2(t+1)[3] +
    // G1(t+2)[4] = 7.
    if (h2)      asm volatile("s_waitcnt vmcnt(7)" ::: "memory");
    else if (h1) asm volatile("s_waitcnt vmcnt(3)" ::: "memory");
    else         asm volatile("s_waitcnt vmcnt(0)" ::: "memory");
    __builtin_amdgcn_s_barrier();
  }

  // ---- epilogue ----
#pragma unroll
  for (int fi = 0; fi < 4; ++fi)
#pragma unroll
    for (int g = 0; g < 6; ++g)
#pragma unroll
      for (int r = 0; r < 4; ++r) {
        const int row = tm + wmi * 64 + fi * 16 + quad * 4 + r;
        const int col = tn + wni * 96 + g * 16 + l16;
        storeC(&C[(size_t)row * N + col], acc[fi][g][r]);
      }
}

// ---------------- C = A (M,K) @ B^T (N,K), 256x128 2-phase (R13) ------------
// grid = (M/256)*(N/128); 8 waves as 4Mx2N, per-wave 64x64, BK=64 = 2 k32
// phases. LDS 96KB (1 block/CU): R13-benched schedule with opening barrier +
// forced lgkmcnt(0) per phase.
template <typename OutT>
__global__ __launch_bounds__(512, 2) void gemm_bn128(const unsigned short* __restrict__ A,
                                                     const unsigned short* __restrict__ B,
                                                     OutT* __restrict__ C,
                                                     int M, int N, int K) {
  __shared__ __align__(16) unsigned short As[2][16384];  // [buf][2][256][32]
  __shared__ __align__(16) unsigned short Bs[2][8192];   // [buf][2][128][32]
  const int tid  = threadIdx.x;
  const int wave = tid >> 6, lane = tid & 63;
  const int quad = lane >> 4, l16 = lane & 15;
  const int wmi  = wave >> 1, wni = wave & 1;            // 4M x 2N wave grid
  const int sx   = ((l16 >> 3) & 1) << 5;

  const int tmn  = M >> 8;
  const int qq   = gridDim.x >> 3;
  const int swzb = (blockIdx.x & 7) * qq + (blockIdx.x >> 3);
  const int tm   = (swzb % tmn) << 8;
  const int tn   = (swzb / tmn) << 7;

  const int logl = (lane * 16) ^ (((lane >> 5) & 1) << 5);
  const int srow = logl >> 6;           // 0..15
  const int scol = (logl & 63) >> 1;    // 0..31
  const int NT   = K >> 6;

  auto issueA = [&](int tt, int ch) {
    glds16(&A[(size_t)(tm + (ch & 15) * 16 + srow) * K + (tt << 6) + (ch >> 4) * 32 + scol],
           (const char*)As + ((tt & 1) << 15) + ch * 1024);
  };
  auto issueB = [&](int tt, int ch) {
    glds16(&B[(size_t)(tn + (ch & 7) * 16 + srow) * K + (tt << 6) + (ch >> 3) * 32 + scol],
           (const char*)Bs + ((tt & 1) << 14) + ch * 1024);
  };

  f32x4 acc[4][4];
#pragma unroll
  for (int i = 0; i < 4; ++i)
#pragma unroll
    for (int j = 0; j < 4; ++j) acc[i][j] = fzero4();

  // prologue: t0-kh0, t0-kh1, t1-kh0 (3 groups x 3 chunks/wave)
  issueB(0, wave);     issueA(0, wave);      issueA(0, 8 + wave);
  issueB(0, 8 + wave); issueA(0, 16 + wave); issueA(0, 24 + wave);
  if (NT > 1) {
    issueB(1, wave); issueA(1, wave); issueA(1, 8 + wave);
    asm volatile("s_waitcnt vmcnt(6)" ::: "memory");
  } else {
    asm volatile("s_waitcnt vmcnt(3)" ::: "memory");
  }
  __builtin_amdgcn_s_barrier();

  for (int t = 0; t < NT; ++t) {
    const char* Asc = (const char*)As + ((t & 1) << 15);
    const char* Bsc = (const char*)Bs + ((t & 1) << 14);
    const bool h1 = (t + 1 < NT), h2 = (t + 2 < NT);
    bf16x8 aq[4], bq[4];

    // ---- phase 0: kh0 ----
#pragma unroll
    for (int g = 0; g < 4; ++g)
      bq[g] = *reinterpret_cast<const bf16x8*>(
          Bsc + (((wni * 64 + g * 16 + l16) << 6) + ((quad * 16) ^ sx)));
#pragma unroll
    for (int f = 0; f < 4; ++f)
      aq[f] = *reinterpret_cast<const bf16x8*>(
          Asc + (((wmi * 64 + f * 16 + l16) << 6) + ((quad * 16) ^ sx)));
    if (h1) {  // (t+1)-kh1 -> idle buffer
      issueB(t + 1, 8 + wave); issueA(t + 1, 16 + wave); issueA(t + 1, 24 + wave);
    }
    __builtin_amdgcn_s_barrier();
    asm volatile("s_waitcnt lgkmcnt(0)" ::: "memory");
    __builtin_amdgcn_s_setprio(1);
#pragma unroll
    for (int f = 0; f < 4; ++f)
#pragma unroll
      for (int g = 0; g < 4; ++g) acc[f][g] = MFMA16(aq[f], bq[g], acc[f][g]);
    __builtin_amdgcn_s_setprio(0);
    if (h1) asm volatile("s_waitcnt vmcnt(6)" ::: "memory");
    else    asm volatile("s_waitcnt vmcnt(0)" ::: "memory");
    __builtin_amdgcn_s_barrier();

    // ---- phase 1: kh1 ----
#pragma unroll
    for (int g = 0; g < 4; ++g)
      bq[g] = *reinterpret_cast<const bf16x8*>(
          Bsc + (8192 + ((wni * 64 + g * 16 + l16) << 6) + ((quad * 16) ^ sx)));
#pragma unroll
    for (int f = 0; f < 4; ++f)
      aq[f] = *reinterpret_cast<const bf16x8*>(
          Asc + (16384 + ((wmi * 64 + f * 16 + l16) << 6) + ((quad * 16) ^ sx)));
    if (h2) {  // (t+2)-kh0 -> current buffer; reads retired at ph0 barrier.
      issueB(t + 2, wave); issueA(t + 2, wave); issueA(t + 2, 8 + wave);
    }
    __builtin_amdgcn_s_barrier();
    asm volatile("s_waitcnt lgkmcnt(0)" ::: "memory");
    __builtin_amdgcn_s_setprio(1);
#pragma unroll
    for (int f = 0; f < 4; ++f)
#pragma unroll
      for (int g = 0; g < 4; ++g) acc[f][g] = MFMA16(aq[f], bq[g], acc[f][g]);
    __builtin_amdgcn_s_setprio(0);
    if (h2)      asm volatile("s_waitcnt vmcnt(6)" ::: "memory");
    else if (h1) asm volatile("s_waitcnt vmcnt(3)" ::: "memory");
    else         asm volatile("s_waitcnt vmcnt(0)" ::: "memory");
    __builtin_amdgcn_s_barrier();
  }

  // ---- epilogue ----
#pragma unroll
  for (int fi = 0; fi < 4; ++fi)
#pragma unroll
    for (int g = 0; g < 4; ++g)
#pragma unroll
      for (int r = 0; r < 4; ++r) {
        const int row = tm + wmi * 64 + fi * 16 + quad * 4 + r;
        const int col = tn + wni * 64 + g * 16 + l16;
        storeC(&C[(size_t)row * N + col], acc[fi][g][r]);
      }
}

// ---------------- K/V fragment packing, LDS-bounced (R18) -------------------
// Same output layouts as R13:
// Kp: per (bk,kt64) 8192-elem block; elem ((c*4+nt)*64+quad*16+l16s)*8+j =
//     K[key=l16s*4+nt][c*32+quad*8+j]
// Vp: per (bk,kt32) 4096-elem block; elem (dt*64+qv*16+l16v)*8+jv =
//     V[key=qv*8+jv][dt*16+l16v]
// Build the packed images in LDS (XOR involution byte^=((byte>>8)&7)<<4 on
// both sides to break bank collisions), then coalesced 16B/lane stores.
__global__ __launch_bounds__(256) void kvpack(const unsigned short* __restrict__ QKV,
                                              unsigned short* __restrict__ Kp,
                                              unsigned short* __restrict__ Vp) {
  __shared__ __align__(16) unsigned short Kl[8192];   // packed K image, 16KB
  __shared__ __align__(16) unsigned short Vl[8192];   // packed V image (2 kt32)
  const int tid  = threadIdx.x;
  const int kt64 = blockIdx.x;           // 0..31
  const int bk   = blockIdx.y;           // b*4 + kvh
  const int b = bk >> 2, kvh = bk & 3;
  const int kt = kt64 * 64;
  const int bT = b * T_SEQ;
  const int dq = tid & 15;               // dim octet: dims dq*8..dq*8+7

  // ---- K: float4 (8 dims = 8 packed-contiguous elems) -> swizzled LDS ----
#pragma unroll
  for (int it = 0; it < 4; ++it) {
    int key = it * 16 + (tid >> 4);      // 0..63
    float4 v = *reinterpret_cast<const float4*>(
        &QKV[(size_t)(bT + kt + key) * QKVN + 2048 + kvh * HS + dq * 8]);
    int c = dq >> 2, quad = dq & 3, nt = key & 3, l16s = key >> 2;
    int byte = ((c * 4 + nt) * 64 + quad * 16 + l16s) * 16;   // elem*2, j=0
    byte ^= ((byte >> 8) & 7) << 4;
    *reinterpret_cast<float4*>((char*)Kl + byte) = v;
  }

  // ---- V: key-pairs -> u32 per dim -> swizzled LDS ----
#pragma unroll
  for (int it = 0; it < 2; ++it) {
    int kp   = it * 16 + (tid >> 4);     // key pair 0..31; keys 2kp, 2kp+1
    int key0 = kp * 2;
    float4 v0 = *reinterpret_cast<const float4*>(
        &QKV[(size_t)(bT + kt + key0) * QKVN + 2560 + kvh * HS + dq * 8]);
    float4 v1 = *reinterpret_cast<const float4*>(
        &QKV[(size_t)(bT + kt + key0 + 1) * QKVN + 2560 + kvh * HS + dq * 8]);
    const unsigned short* p0 = reinterpret_cast<const unsigned short*>(&v0);
    const unsigned short* p1 = reinterpret_cast<const unsigned short*>(&v1);
    int qv  = (kp & 15) >> 2;            // (key0&31)>>3 (key0 even)
    int jv  = (kp & 3) * 2;              // key0&7, even
    int blk = kp >> 4;                   // key0>>5
#pragma unroll
    for (int j2 = 0; j2 < 8; ++j2) {
      int d = dq * 8 + j2, dt = d >> 4, l16v = d & 15;
      int byte = (blk * 4096 + (dt * 64 + qv * 16 + l16v) * 8 + jv) * 2;
      byte ^= ((byte >> 8) & 7) << 4;
      unsigned int u = (unsigned int)p0[j2] | ((unsigned int)p1[j2] << 16);
      *reinterpret_cast<unsigned int*>((char*)Vl + byte) = u;
    }
  }
  __syncthreads();

  // ---- coalesced store-out: linear global, swizzled LDS read ----
  char* kdst = (char*)&Kp[(size_t)(bk * 32 + kt64) * 8192];
  char* vdst = (char*)&Vp[(size_t)(bk * 64 + kt64 * 2) * 4096];  // 2 blocks contiguous
#pragma unroll
  for (int it = 0; it < 4; ++it) {
    int byte = it * 4096 + tid * 16;
    int sb   = byte ^ (((byte >> 8) & 7) << 4);
    *reinterpret_cast<uint4*>(kdst + byte) =
        *reinterpret_cast<const uint4*>((const char*)Kl + sb);
    *reinterpret_cast<uint4*>(vdst + byte) =
        *reinterpret_cast<const uint4*>((const char*)Vl + sb);
  }
}

// ---------------- flash attention, 1-barrier chunk loop (R20) ---------------
// grid 512 = 64 q-tiles x 8 (b,kvh); bk = blockIdx.x & 7 so all q-tiles of a
// KV group land on one XCD (round-robin dispatch) -> K/V L2-resident.
// block 256 = 4 waves = 4 heads of the group, same 32 queries. Per chunk:
// vmcnt(0) drains this wave's stage(ci) loads (issued a full chunk ago);
// barrier publishes all parts AND retires all waves' buf^1 reads; then
// stage(ci+1) into buf^1 (restage-safe) and compute from buf.
// P tile: per-wave [32 rows][64 elems] linear, XOR swizzle byte^=(row&7)<<4
// on both the uint2 write and b128 read (alignment preserved, bits 4-6).
__global__ __launch_bounds__(256) void attn_kernel(const unsigned short* __restrict__ QKV,
                                                   const unsigned short* __restrict__ Kp,
                                                   const unsigned short* __restrict__ Vp,
                                                   unsigned short* __restrict__ Y) {
  __shared__ __align__(16) unsigned short Ks[2][8192];
  __shared__ __align__(16) unsigned short Vs[2][8192];
  __shared__ __align__(16) unsigned short Ps[4 * 2048];   // [wave][32][64]

  const int tid  = threadIdx.x;
  const int wave = tid >> 6, lane = tid & 63;
  const int quad = lane >> 4, l16 = lane & 15;
  const int bk   = blockIdx.x & 7;                        // XCD-resident group
  const int seq  = blockIdx.x >> 3;                       // 0..63
  const int qt0  = (63 - seq) * 32;                       // long blocks first
  const int kvh  = bk & 3, b = bk >> 2;
  const int h    = kvh * 4 + wave;
  const int bT   = b * T_SEQ;
  char* Pw = (char*)&Ps[wave * 2048];

  // Q fragments (A-operand: m=l16, k=quad*8+j); Q pre-scaled by log2e/sqrt(HS)
  bf16x8 qa[2][4];
#pragma unroll
  for (int mt = 0; mt < 2; ++mt)
#pragma unroll
    for (int c = 0; c < 4; ++c)
      qa[mt][c] = *reinterpret_cast<const bf16x8*>(
          &QKV[(size_t)(bT + qt0 + mt * 16 + l16) * QKVN + h * HS + c * 32 + quad * 8]);

  bf16x8 ones;
#pragma unroll
  for (int j = 0; j < 8; ++j) ones[j] = us2b(0x3F80);  // bf16 1.0

  f32x4 o[2][9];   // [mt][dt]; dt=8 accumulates row-sum l
#pragma unroll
  for (int mt = 0; mt < 2; ++mt)
#pragma unroll
    for (int dt = 0; dt < 9; ++dt) o[mt][dt] = fzero4();

  const int start = (qt0 >= 1024) ? ((qt0 - 1023) & ~63) : 0;
  const int sink  = (start > 0) ? 1 : 0;
  const int nch   = ((qt0 + 32 - start + 63) >> 6) + sink;

  // stage chunk ci into buffer buf (8 glds16/wave: 4 K parts + 4 V parts)
  auto stage = [&](int ci, int buf) {
    const int kt = (sink && ci == 0) ? 0 : start + (ci - sink) * 64;
    const unsigned short* kg = &Kp[(size_t)(bk * 32 + (kt >> 6)) * 8192 + lane * 8];
    const unsigned short* vg = &Vp[(size_t)(bk * 64 + (kt >> 5)) * 4096 + lane * 8];
#pragma unroll
    for (int i = 0; i < 4; ++i) {
      int part = wave * 4 + i;                    // wave-uniform
      glds16(kg + part * 512, &Ks[buf][part * 512]);
      glds16(vg + part * 512, &Vs[buf][part * 512]);
    }
  };

  stage(0, 0);

  for (int ci = 0; ci < nch; ++ci) {
    const int  buf = ci & 1;
    const bool is_sink = (sink && ci == 0);
    const int  kt  = is_sink ? 0 : start + (ci - sink) * 64;
    const int  rem = qt0 + 32 - kt;
    const int  kcmax = is_sink ? 1 : (rem >= 64 ? 2 : ((rem + 31) >> 5));
    const bool full  = !is_sink && (kt + 63 <= qt0) && (kt >= qt0 - 992);

    // drain own stage(ci) loads (issued a full chunk ago), then publish.
    asm volatile("s_waitcnt vmcnt(0)" ::: "memory");
    __builtin_amdgcn_s_barrier();
    // barrier also proves all waves' reads of buf^1 (iteration ci-1) retired
    // -> restage of buf^1 is safe from here.
    if (ci + 1 < nch) stage(ci + 1, buf ^ 1);

    // ---- S = Q K^T from LDS (conflict-free b128 reads) ----
    f32x4 s[2][4];
#pragma unroll
    for (int nt = 0; nt < 4; ++nt) { s[0][nt] = fzero4(); s[1][nt] = fzero4(); }
    __builtin_amdgcn_s_setprio(1);
#pragma unroll
    for (int c = 0; c < 4; ++c) {
#pragma unroll
      for (int nt = 0; nt < 4; ++nt) {
        bf16x8 kf = *reinterpret_cast<const bf16x8*>(&Ks[buf][(c * 4 + nt) * 512 + lane * 8]);
        s[0][nt] = MFMA16(qa[0][c], kf, s[0][nt]);
        s[1][nt] = MFMA16(qa[1][c], kf, s[1][nt]);
      }
    }
    __builtin_amdgcn_s_setprio(0);

    // ---- P = exp2(S) with mask (key of col: kt + l16*4 + nt) ----
    // write: elems [l16*4 .. l16*4+3] of row -> byte (row*128+l16*8)^((row&7)<<4)
    if (full) {
#pragma unroll
      for (int mt = 0; mt < 2; ++mt)
#pragma unroll
        for (int r = 0; r < 4; ++r) {
          const int row = mt * 16 + quad * 4 + r;
          uint2 pk;
          pk.x = pkhi(EXP2(s[mt][0][r]), EXP2(s[mt][1][r]));
          pk.y = pkhi(EXP2(s[mt][2][r]), EXP2(s[mt][3][r]));
          *reinterpret_cast<uint2*>(
              Pw + ((row * 128 + l16 * 8) ^ ((row & 7) << 4))) = pk;
        }
    } else {
#pragma unroll
      for (int mt = 0; mt < 2; ++mt)
#pragma unroll
        for (int r = 0; r < 4; ++r) {
          const int row = mt * 16 + quad * 4 + r;
          const int qi  = qt0 + row;
          float p[4];
#pragma unroll
          for (int nt = 0; nt < 4; ++nt) {
            int kj = kt + l16 * 4 + nt;
            bool ok = ((kj <= qi) && (kj + (WIN - 1) >= qi)) ||
                      ((kj < SINKN) && (qi >= SINKN));
            p[nt] = ok ? EXP2(s[mt][nt][r]) : 0.f;
          }
          uint2 pk;
          pk.x = pkhi(p[0], p[1]);
          pk.y = pkhi(p[2], p[3]);
          *reinterpret_cast<uint2*>(
              Pw + ((row * 128 + l16 * 8) ^ ((row & 7) << 4))) = pk;
        }
    }
    asm volatile("s_waitcnt lgkmcnt(0)" ::: "memory");  // wave-local P drain

    // ---- O += P V (+ ones column for l), V from LDS ----
    __builtin_amdgcn_s_setprio(1);
#pragma unroll
    for (int kc = 0; kc < 2; ++kc)
      if (kc < kcmax) {
#pragma unroll
        for (int mt = 0; mt < 2; ++mt) {
          const int prow = mt * 16 + l16;
          bf16x8 pf = *reinterpret_cast<const bf16x8*>(
              Pw + ((prow * 128 + kc * 64 + quad * 16) ^ ((prow & 7) << 4)));
#pragma unroll
          for (int dt = 0; dt < 8; ++dt) {
            bf16x8 vf = *reinterpret_cast<const bf16x8*>(
                &Vs[buf][kc * 4096 + dt * 512 + lane * 8]);
            o[mt][dt] = MFMA16(pf, vf, o[mt][dt]);
          }
          o[mt][8] = MFMA16(pf, ones, o[mt][8]);
        }
      }
    __builtin_amdgcn_s_setprio(0);
  }

  // ---- normalize, stage in LDS (reuse Ks), coalesced Y store ----
  __syncthreads();                       // full drain before buffer reuse
  unsigned short* Yst = &Ks[0][0];       // 32 rows x 512 cols (32KB)
#pragma unroll
  for (int mt = 0; mt < 2; ++mt) {
    float inv[4];
#pragma unroll
    for (int r = 0; r < 4; ++r) inv[r] = __builtin_amdgcn_rcpf(o[mt][8][r]);
#pragma unroll
    for (int dt = 0; dt < 8; ++dt)
#pragma unroll
      for (int r = 0; r < 4; ++r)
        Yst[(mt * 16 + quad * 4 + r) * 512 + wave * 128 + dt * 16 + l16] =
            f2bu(o[mt][dt][r] * inv[r]);
  }
  __syncthreads();
#pragma unroll
  for (int it = 0; it < 8; ++it) {
    int idx = it * 256 + tid;
    int row = idx >> 6, col = (idx & 63) * 8;
    *reinterpret_cast<uint4*>(
        &Y[(size_t)(bT + qt0 + row) * CDIM + kvh * 512 + col]) =
        *reinterpret_cast<const uint4*>(&Yst[row * 512 + col]);
  }
}

// ---------------------------------------------------------------------------
extern "C" void kernel_launch(void* const* d_in, const int* in_sizes, int n_in,
                              void* d_out, int out_size, void* d_ws, size_t ws_size,
                              hipStream_t stream) {
  const float* x  = (const float*)d_in[0];
  const float* Wq = (const float*)d_in[1];
  const float* Wk = (const float*)d_in[2];
  const float* Wv = (const float*)d_in[3];
  const float* Wo = (const float*)d_in[4];
  float* out = (float*)d_out;

  // workspace layout (bf16 elems); total 62.9 MB
  unsigned short* base = (unsigned short*)d_ws;
  unsigned short* xb   = base;              // x bf16 (8388608); later Y
  unsigned short* wqb  = xb + OFF_WQ;       // Wq bf16; later Kp+Vp
  unsigned short* wob  = xb + OFF_WO;       // Wo bf16
  unsigned short* QKVb = xb + SZ_ALL;       // QKV (4096 x 3072)
  unsigned short* Kpb  = wqb;               // packed K (2097152)
  unsigned short* Vpb  = wqb + 2097152;     // packed V (2097152)
  unsigned short* Yb   = xb;                // attn out (4096 x 2048)

  // 1/sqrt(HS) * log2(e) folded into Wq so exp2 is native
  const float qscale = 0.08838834764831845f * 1.4426950408889634f;
  f2b_all<<<SZ_ALL / 1024, 256, 0, stream>>>(x, Wq, Wk, Wv, Wo, xb, qscale);

  // fused QKV projection: 256x192 tiles -> 16x16 = 256 blocks (full GPU)
  gemm_bn192<unsigned short><<<256, 512, 0, stream>>>(xb, wqb, QKVb, 4096, QKVN, 2048);

  kvpack<<<dim3(32, 8), 256, 0, stream>>>(QKVb, Kpb, Vpb);

  // attention: 1D grid, bk = id&7 -> per-XCD K/V residency
  attn_kernel<<<512, 256, 0, stream>>>(QKVb, Kpb, Vpb, Yb);

  // output projection: 256x128 tiles -> 16x16 = 256 blocks (R13 config)
  gemm_bn128<float><<<256, 512, 0, stream>>>(Yb, wob, out, 4096, 2048, 2048);
}